// Round 2
// baseline (670.544 us; speedup 1.0000x reference)
//
#include <hip/hip_runtime.h>

#define DD 128
#define GG 500
#define NSTK 100
#define SLOPE 0.2f
#define BN_EPS 1e-5f

// ---------------- CSR build ----------------

__global__ __launch_bounds__(256) void hist_kernel(const int* __restrict__ dst,
                                                   int* __restrict__ deg, int e_count) {
    int e = blockIdx.x * 256 + threadIdx.x;
    if (e < e_count) atomicAdd(&deg[dst[e]], 1);
}

__global__ __launch_bounds__(256) void offsets_kernel(const int* __restrict__ deg,
                                                      int* __restrict__ start,
                                                      int* __restrict__ cursor,
                                                      int* __restrict__ total, int n) {
    int i = blockIdx.x * 256 + threadIdx.x;
    int lane = threadIdx.x & 63;
    int d = (i < n) ? deg[i] : 0;
    int pre = d;
    #pragma unroll
    for (int off = 1; off < 64; off <<= 1) {
        int t = __shfl_up(pre, off, 64);
        if (lane >= off) pre += t;
    }
    int wavesum = __shfl(pre, 63, 64);
    int base = 0;
    if (lane == 0) base = atomicAdd(total, wavesum);
    base = __shfl(base, 0, 64);
    if (i < n) {
        int s0 = base + pre - d;
        start[i] = s0;
        cursor[i] = s0;
    }
}

__global__ __launch_bounds__(256) void scatter_kernel(const int* __restrict__ src,
                                                      const int* __restrict__ dst,
                                                      int* __restrict__ cursor,
                                                      int* __restrict__ csr_src, int e_count) {
    int e = blockIdx.x * 256 + threadIdx.x;
    if (e < e_count) {
        int d = dst[e];
        int p = atomicAdd(&cursor[d], 1);
        csr_src[p] = src[e];
    }
}

__global__ void bn_prep_kernel(const float* __restrict__ g, const float* __restrict__ b,
                               const float* __restrict__ m, const float* __restrict__ v,
                               float* __restrict__ scale, float* __restrict__ shift) {
    int i = threadIdx.x;
    float s = g[i] * rsqrtf(v[i] + BN_EPS);
    scale[i] = s;
    shift[i] = b[i] - m[i] * s;
}

// ---------------- dual matmul: outA = x@wA + bA ; outB = x@wB + bB ----------------
// 64 rows x 128 cols per block; 8x4 outputs/thread; W staged in 64-row halves.
// FMA:LDS-instr ratio 128:12 per k4 step (vs 64:8 in v1) -> VALU-bound.

__global__ __launch_bounds__(256) void dualmm_kernel(
    const float* __restrict__ x,
    const float* __restrict__ wA, const float* __restrict__ bA, float* __restrict__ outA,
    const float* __restrict__ wB, const float* __restrict__ bB, float* __restrict__ outB,
    int n)
{
    __shared__ float xs[64][DD];     // 32 KB
    __shared__ float wsh[64][DD];    // 32 KB
    int t = threadIdx.x;
    int row0 = blockIdx.x * 64;

    // stage x tile: 8192 floats, 8 float4 per thread
    #pragma unroll
    for (int i = 0; i < 8; ++i) {
        int idx = (i * 256 + t) * 4;
        int r = idx >> 7, c = idx & 127;
        float4 v = make_float4(0.f, 0.f, 0.f, 0.f);
        if (row0 + r < n) v = *(const float4*)&x[(size_t)(row0 + r) * DD + c];
        *(float4*)&xs[r][c] = v;
    }

    int col = (t & 31) * 4;        // output col base
    int rbase = (t >> 5) * 8;      // output row base within tile (8 rows/thread)

    const float* wmat[2] = {wA, wB};
    const float* bvec[2] = {bA, bB};
    float* omat[2] = {outA, outB};

    for (int side = 0; side < 2; ++side) {
        float acc[8][4];
        #pragma unroll
        for (int m = 0; m < 8; ++m)
            #pragma unroll
            for (int c = 0; c < 4; ++c) acc[m][c] = 0.f;
        const float* w = wmat[side];
        for (int half = 0; half < 2; ++half) {
            __syncthreads();
            #pragma unroll
            for (int i = 0; i < 8; ++i) {
                int idx = (i * 256 + t) * 4;
                int r = idx >> 7, c = idx & 127;
                *(float4*)&wsh[r][c] = *(const float4*)&w[(size_t)(half * 64 + r) * DD + c];
            }
            __syncthreads();
            #pragma unroll
            for (int k4 = 0; k4 < 16; ++k4) {
                int kb = half * 64 + k4 * 4;
                float4 wv0 = *(const float4*)&wsh[k4 * 4 + 0][col];
                float4 wv1 = *(const float4*)&wsh[k4 * 4 + 1][col];
                float4 wv2 = *(const float4*)&wsh[k4 * 4 + 2][col];
                float4 wv3 = *(const float4*)&wsh[k4 * 4 + 3][col];
                #pragma unroll
                for (int m = 0; m < 8; ++m) {
                    float4 xv = *(const float4*)&xs[rbase + m][kb];
                    acc[m][0] += xv.x * wv0.x + xv.y * wv1.x + xv.z * wv2.x + xv.w * wv3.x;
                    acc[m][1] += xv.x * wv0.y + xv.y * wv1.y + xv.z * wv2.y + xv.w * wv3.y;
                    acc[m][2] += xv.x * wv0.z + xv.y * wv1.z + xv.z * wv2.z + xv.w * wv3.z;
                    acc[m][3] += xv.x * wv0.w + xv.y * wv1.w + xv.z * wv2.w + xv.w * wv3.w;
                }
            }
        }
        float4 bb = *(const float4*)&bvec[side][col];
        #pragma unroll
        for (int m = 0; m < 8; ++m) {
            int r = row0 + rbase + m;
            if (r < n) {
                float4 o;
                o.x = acc[m][0] + bb.x; o.y = acc[m][1] + bb.y;
                o.z = acc[m][2] + bb.z; o.w = acc[m][3] + bb.w;
                *(float4*)&omat[side][(size_t)r * DD + col] = o;
            }
        }
    }
}

// ---------------- fused GATv2 edge phase: one wave per dst node ----------------
// 4 lane-groups of 16; group g handles edges j = g, g+4, ... -> 4 gather chains
// in flight. Lane l of a group covers dims l*8..l*8+7.
// e = att . lrelu(xl[src] + xr[dst]); p = exp(e) (softmax shift-invariant, logits O(1))

__global__ __launch_bounds__(256) void gat_agg_kernel(
    const float* __restrict__ xl, const float* __restrict__ xr,
    const int* __restrict__ row_start, const int* __restrict__ degv,
    const int* __restrict__ csr_src,
    const float* __restrict__ att, const float* __restrict__ bias,
    const float* __restrict__ bn_scale, const float* __restrict__ bn_shift,
    float* __restrict__ out, int n, int use_bn)
{
    int wave = (int)((blockIdx.x * 256 + threadIdx.x) >> 6);
    int lane = threadIdx.x & 63;
    if (wave >= n) return;
    int grp = lane >> 4;        // 0..3
    int gl  = lane & 15;        // 0..15
    int f   = gl * 8;           // dim base

    float4 xr0 = *(const float4*)&xr[(size_t)wave * DD + f];
    float4 xr1 = *(const float4*)&xr[(size_t)wave * DD + f + 4];
    float4 at0 = *(const float4*)&att[f];
    float4 at1 = *(const float4*)&att[f + 4];

    int nstart = row_start[wave];
    int deg = degv[wave];

    float acc[8] = {0.f, 0.f, 0.f, 0.f, 0.f, 0.f, 0.f, 0.f};
    float den = 0.f;

    for (int j = grp; j < deg; j += 4) {
        int s = csr_src[nstart + j];
        const float* xp = &xl[(size_t)s * DD + f];
        float4 a0 = *(const float4*)xp;
        float4 a1 = *(const float4*)(xp + 4);
        float t, partial;
        t = a0.x + xr0.x; t = t > 0.f ? t : SLOPE * t; partial  = at0.x * t;
        t = a0.y + xr0.y; t = t > 0.f ? t : SLOPE * t; partial += at0.y * t;
        t = a0.z + xr0.z; t = t > 0.f ? t : SLOPE * t; partial += at0.z * t;
        t = a0.w + xr0.w; t = t > 0.f ? t : SLOPE * t; partial += at0.w * t;
        t = a1.x + xr1.x; t = t > 0.f ? t : SLOPE * t; partial += at1.x * t;
        t = a1.y + xr1.y; t = t > 0.f ? t : SLOPE * t; partial += at1.y * t;
        t = a1.z + xr1.z; t = t > 0.f ? t : SLOPE * t; partial += at1.z * t;
        t = a1.w + xr1.w; t = t > 0.f ? t : SLOPE * t; partial += at1.w * t;
        // reduce across the 16 lanes of this group
        partial += __shfl_xor(partial, 1, 64);
        partial += __shfl_xor(partial, 2, 64);
        partial += __shfl_xor(partial, 4, 64);
        partial += __shfl_xor(partial, 8, 64);
        float p = __expf(partial);
        den += p;
        acc[0] += p * a0.x; acc[1] += p * a0.y; acc[2] += p * a0.z; acc[3] += p * a0.w;
        acc[4] += p * a1.x; acc[5] += p * a1.y; acc[6] += p * a1.z; acc[7] += p * a1.w;
    }

    // combine the 4 groups (dim layout replicated across groups)
    #pragma unroll
    for (int k = 0; k < 8; ++k) {
        acc[k] += __shfl_xor(acc[k], 16, 64);
        acc[k] += __shfl_xor(acc[k], 32, 64);
    }
    den += __shfl_xor(den, 16, 64);
    den += __shfl_xor(den, 32, 64);

    if (grp == 0) {
        float inv = (deg > 0) ? 1.0f / den : 0.0f;
        float o[8];
        #pragma unroll
        for (int k = 0; k < 8; ++k) o[k] = acc[k] * inv + bias[f + k];
        if (use_bn) {
            #pragma unroll
            for (int k = 0; k < 8; ++k) {
                o[k] = o[k] * bn_scale[f + k] + bn_shift[f + k];
                o[k] = o[k] > 0.f ? o[k] : 0.f;
            }
        }
        *(float4*)&out[(size_t)wave * DD + f]     = make_float4(o[0], o[1], o[2], o[3]);
        *(float4*)&out[(size_t)wave * DD + f + 4] = make_float4(o[4], o[5], o[6], o[7]);
    }
}

// ---------------- global mean pool ----------------

__device__ __forceinline__ int lower_bound_dev(const int* __restrict__ arr, int n, int val) {
    int lo = 0, hi = n;
    while (lo < hi) {
        int mid = (lo + hi) >> 1;
        if (arr[mid] < val) lo = mid + 1; else hi = mid;
    }
    return lo;
}

__global__ __launch_bounds__(128) void pool_kernel(const float* __restrict__ h,
                                                   const int* __restrict__ batch,
                                                   float* __restrict__ pooled, int n) {
    int g = blockIdx.x;
    int f = threadIdx.x;
    int lo = lower_bound_dev(batch, n, g);
    int hi = lower_bound_dev(batch, n, g + 1);
    float s = 0.f;
    for (int i = lo; i < hi; ++i) s += h[(size_t)i * DD + f];
    float cnt = (float)(hi - lo);
    pooled[(size_t)g * DD + f] = s / fmaxf(cnt, 1.0f);
}

// ---------------- fused head ----------------

__global__ __launch_bounds__(64) void head_kernel(
    const float* __restrict__ pooled, const float* __restrict__ fc1_w,
    const float* __restrict__ fc1_b, const float* __restrict__ fc3_w,
    const float* __restrict__ fc3_b, float* __restrict__ out)
{
    int sIdx = blockIdx.x;      // 0..99
    int gbase = blockIdx.y * 20;
    int j = threadIdx.x;        // 0..63

    float wreg[DD];
    #pragma unroll
    for (int k = 0; k < DD; ++k)
        wreg[k] = fc1_w[(size_t)k * (NSTK * 64) + sIdx * 64 + j];
    float b1 = fc1_b[sIdx * 64 + j];
    float w3 = fc3_w[j];
    float b3 = fc3_b[0];

    for (int gi = 0; gi < 20; ++gi) {
        int g = gbase + gi;
        float acc = b1;
        #pragma unroll
        for (int k4 = 0; k4 < DD / 4; ++k4) {
            float4 pv = *(const float4*)&pooled[(size_t)g * DD + k4 * 4];
            acc += pv.x * wreg[k4 * 4 + 0];
            acc += pv.y * wreg[k4 * 4 + 1];
            acc += pv.z * wreg[k4 * 4 + 2];
            acc += pv.w * wreg[k4 * 4 + 3];
        }
        float r = acc > 0.f ? acc : 0.f;
        float v = r * w3;
        #pragma unroll
        for (int off = 32; off; off >>= 1) v += __shfl_xor(v, off, 64);
        if (j == 0) out[(size_t)g * NSTK + sIdx] = 1.0f / (1.0f + __expf(-(v + b3)));
    }
}

// ---------------- launch ----------------

extern "C" void kernel_launch(void* const* d_in, const int* in_sizes, int n_in,
                              void* d_out, int out_size, void* d_ws, size_t ws_size,
                              hipStream_t stream) {
    const float* x        = (const float*)d_in[0];
    const int*   graph    = (const int*)d_in[1];
    const int*   batch    = (const int*)d_in[2];
    const float* wl0      = (const float*)d_in[3];
    const float* bl0      = (const float*)d_in[4];
    const float* wr0      = (const float*)d_in[5];
    const float* br0      = (const float*)d_in[6];
    const float* att0     = (const float*)d_in[7];
    const float* b0       = (const float*)d_in[8];
    const float* wl1      = (const float*)d_in[9];
    const float* bl1      = (const float*)d_in[10];
    const float* wr1      = (const float*)d_in[11];
    const float* br1      = (const float*)d_in[12];
    const float* att1     = (const float*)d_in[13];
    const float* b1       = (const float*)d_in[14];
    const float* bn_gamma = (const float*)d_in[15];
    const float* bn_beta  = (const float*)d_in[16];
    const float* bn_mean  = (const float*)d_in[17];
    const float* bn_var   = (const float*)d_in[18];
    const float* fc1_w    = (const float*)d_in[19];
    const float* fc1_b    = (const float*)d_in[20];
    const float* fc3_w    = (const float*)d_in[21];
    const float* fc3_b    = (const float*)d_in[22];
    float* out = (float*)d_out;

    int n       = in_sizes[0] / DD;   // 50000
    int e_count = in_sizes[1] / 2;    // 800000
    const int* srcv = graph;
    const int* dstv = graph + e_count;

    float* A        = (float*)d_ws;
    float* B        = A + (size_t)n * DD;
    float* C        = B + (size_t)n * DD;
    float* pooled   = C + (size_t)n * DD;
    float* bn_scale = pooled + (size_t)GG * DD;
    float* bn_shift = bn_scale + DD;
    int* deg     = (int*)(bn_shift + DD);
    int* total   = deg + n;
    int* start   = total + 1;
    int* cursor  = start + n;
    int* csr_src = cursor + n;

    hipMemsetAsync(deg, 0, (size_t)(n + 1) * sizeof(int), stream);
    hist_kernel<<<(e_count + 255) / 256, 256, 0, stream>>>(dstv, deg, e_count);
    offsets_kernel<<<(n + 255) / 256, 256, 0, stream>>>(deg, start, cursor, total, n);
    scatter_kernel<<<(e_count + 255) / 256, 256, 0, stream>>>(srcv, dstv, cursor, csr_src, e_count);
    bn_prep_kernel<<<1, DD, 0, stream>>>(bn_gamma, bn_beta, bn_mean, bn_var, bn_scale, bn_shift);

    int mmblocks = (n + 63) / 64;
    int aggblocks = (n + 3) / 4;

    dualmm_kernel<<<mmblocks, 256, 0, stream>>>(x, wl0, bl0, A, wr0, br0, B, n);
    gat_agg_kernel<<<aggblocks, 256, 0, stream>>>(A, B, start, deg, csr_src, att0, b0,
                                                  bn_scale, bn_shift, C, n, 1);
    dualmm_kernel<<<mmblocks, 256, 0, stream>>>(C, wl1, bl1, A, wr1, br1, B, n);
    gat_agg_kernel<<<aggblocks, 256, 0, stream>>>(A, B, start, deg, csr_src, att1, b1,
                                                  nullptr, nullptr, C, n, 0);
    pool_kernel<<<GG, DD, 0, stream>>>(C, batch, pooled, n);
    head_kernel<<<dim3(NSTK, GG / 20), 64, 0, stream>>>(pooled, fc1_w, fc1_b, fc3_w, fc3_b, out);
}

// Round 3
// 433.703 us; speedup vs baseline: 1.5461x; 1.5461x over previous
//
#include <hip/hip_runtime.h>

#define DD 128
#define GG 500
#define NSTK 100
#define SLOPE 0.2f
#define BN_EPS 1e-5f
#define XPAD 136   // LDS row stride in bf16 elems (128 + 8 pad -> 2-way bank alias only)

typedef __attribute__((ext_vector_type(8))) short bf16x8;
typedef __attribute__((ext_vector_type(4))) float f32x4;

static __device__ __forceinline__ unsigned short f2bf(float f) {
    union { float f; unsigned int u; } v; v.f = f;
    unsigned int r = (v.u + 0x7fff + ((v.u >> 16) & 1)) >> 16;   // RNE
    return (unsigned short)r;
}

// ---------------- CSR build ----------------

__global__ __launch_bounds__(256) void hist_kernel(const int* __restrict__ dst,
                                                   int* __restrict__ deg, int e_count) {
    int e = blockIdx.x * 256 + threadIdx.x;
    if (e < e_count) atomicAdd(&deg[dst[e]], 1);
}

__global__ __launch_bounds__(256) void offsets_kernel(const int* __restrict__ deg,
                                                      int* __restrict__ start,
                                                      int* __restrict__ cursor,
                                                      int* __restrict__ total, int n) {
    int i = blockIdx.x * 256 + threadIdx.x;
    int lane = threadIdx.x & 63;
    int d = (i < n) ? deg[i] : 0;
    int pre = d;
    #pragma unroll
    for (int off = 1; off < 64; off <<= 1) {
        int t = __shfl_up(pre, off, 64);
        if (lane >= off) pre += t;
    }
    int wavesum = __shfl(pre, 63, 64);
    int base = 0;
    if (lane == 0) base = atomicAdd(total, wavesum);
    base = __shfl(base, 0, 64);
    if (i < n) {
        int s0 = base + pre - d;
        start[i] = s0;
        cursor[i] = s0;
    }
}

__global__ __launch_bounds__(256) void scatter_kernel(const int* __restrict__ src,
                                                      const int* __restrict__ dst,
                                                      int* __restrict__ cursor,
                                                      int* __restrict__ csr_src, int e_count) {
    int e = blockIdx.x * 256 + threadIdx.x;
    if (e < e_count) {
        int d = dst[e];
        int p = atomicAdd(&cursor[d], 1);
        csr_src[p] = src[e];
    }
}

__global__ void bn_prep_kernel(const float* __restrict__ g, const float* __restrict__ b,
                               const float* __restrict__ m, const float* __restrict__ v,
                               float* __restrict__ scale, float* __restrict__ shift) {
    int i = threadIdx.x;
    float s = g[i] * rsqrtf(v[i] + BN_EPS);
    scale[i] = s;
    shift[i] = b[i] - m[i] * s;
}

// ---------------- weight prep: WT[c][k] bf16, c in [0,256): [wl | wr] transposed ----------------

__global__ __launch_bounds__(128) void wprep_kernel(
    const float* __restrict__ wl0, const float* __restrict__ wr0,
    const float* __restrict__ wl1, const float* __restrict__ wr1,
    unsigned short* __restrict__ wt0, unsigned short* __restrict__ wt1)
{
    int c = blockIdx.x;          // 0..255
    int layer = blockIdx.y;      // 0..1
    int k = threadIdx.x;         // 0..127
    const float* wl = layer ? wl1 : wl0;
    const float* wr = layer ? wr1 : wr0;
    float v = (c < 128) ? wl[k * DD + c] : wr[k * DD + (c - 128)];
    unsigned short* wt = layer ? wt1 : wt0;
    wt[c * DD + k] = f2bf(v);
}

// ---------------- dual matmul via MFMA: [outA | outB] = x @ [wA | wB] + [bA | bB] ----------------
// block: 64 rows x 128 cols (blockIdx.y picks col-half = which output matrix).
// 4 waves, each 64 rows x 32 cols = 8 MFMA 16x16 tiles, K=128 staged once in LDS.

__global__ __launch_bounds__(256) void dualmm_mfma_kernel(
    const float* __restrict__ x, const unsigned short* __restrict__ wt,
    const float* __restrict__ bA, const float* __restrict__ bB,
    float* __restrict__ outA, float* __restrict__ outB, int n)
{
    __shared__ unsigned short xs[64 * XPAD];    // 17408 B
    __shared__ unsigned short wsh[128 * XPAD];  // 34816 B
    int t = threadIdx.x;
    int row0 = blockIdx.x * 64;
    int half = blockIdx.y;

    // stage x (f32 -> bf16): 8192 elems, 8 per thread per iter
    #pragma unroll
    for (int i = 0; i < 4; ++i) {
        int idx8 = i * 256 + t;            // 0..1023
        int r = idx8 >> 4;                 // 16 chunks of 8 per row
        int c = (idx8 & 15) * 8;
        float4 v0 = make_float4(0.f, 0.f, 0.f, 0.f), v1 = v0;
        if (row0 + r < n) {
            v0 = *(const float4*)&x[(size_t)(row0 + r) * DD + c];
            v1 = *(const float4*)&x[(size_t)(row0 + r) * DD + c + 4];
        }
        union { bf16x8 v; unsigned short u[8]; } pk;
        pk.u[0] = f2bf(v0.x); pk.u[1] = f2bf(v0.y); pk.u[2] = f2bf(v0.z); pk.u[3] = f2bf(v0.w);
        pk.u[4] = f2bf(v1.x); pk.u[5] = f2bf(v1.y); pk.u[6] = f2bf(v1.z); pk.u[7] = f2bf(v1.w);
        *(bf16x8*)&xs[r * XPAD + c] = pk.v;
    }
    // stage WT rows [half*128, half*128+128): 128 rows x 256 B, uint4 copies
    #pragma unroll
    for (int i = 0; i < 8; ++i) {
        int idx = i * 256 + t;             // 0..2047 chunks of 16 B
        int r = idx >> 4;
        int ck = (idx & 15) * 8;           // bf16 elem offset within row
        uint4 v = *(const uint4*)&wt[(size_t)(half * 128 + r) * DD + ck];
        *(uint4*)&wsh[r * XPAD + ck] = v;
    }
    __syncthreads();

    int wave = t >> 6, lane = t & 63;
    int m16 = lane & 15;
    int kg = lane >> 4;                    // 0..3

    f32x4 acc[4][2];
    #pragma unroll
    for (int rt = 0; rt < 4; ++rt)
        #pragma unroll
        for (int ct = 0; ct < 2; ++ct)
            acc[rt][ct] = (f32x4){0.f, 0.f, 0.f, 0.f};

    #pragma unroll
    for (int ks = 0; ks < 4; ++ks) {
        int koff = ks * 32 + kg * 8;
        bf16x8 a[4], b[2];
        #pragma unroll
        for (int rt = 0; rt < 4; ++rt)
            a[rt] = *(bf16x8*)&xs[(rt * 16 + m16) * XPAD + koff];
        #pragma unroll
        for (int ct = 0; ct < 2; ++ct)
            b[ct] = *(bf16x8*)&wsh[(wave * 32 + ct * 16 + m16) * XPAD + koff];
        #pragma unroll
        for (int rt = 0; rt < 4; ++rt)
            #pragma unroll
            for (int ct = 0; ct < 2; ++ct)
                acc[rt][ct] = __builtin_amdgcn_mfma_f32_16x16x32_bf16(a[rt], b[ct], acc[rt][ct], 0, 0, 0);
    }

    const float* bias = half ? bB : bA;
    float* outp = half ? outB : outA;
    int colb = wave * 32;
    #pragma unroll
    for (int rt = 0; rt < 4; ++rt) {
        int r = row0 + rt * 16 + kg * 4;   // C/D layout: row = (lane>>4)*4 + reg
        #pragma unroll
        for (int ct = 0; ct < 2; ++ct) {
            int c = colb + ct * 16 + m16;  // col = lane&15
            float bb = bias[c];
            #pragma unroll
            for (int i = 0; i < 4; ++i) {
                if (r + i < n)
                    outp[(size_t)(r + i) * DD + c] = acc[rt][ct][i] + bb;
            }
        }
    }
}

// ---------------- fused GATv2 edge phase: one wave per dst node ----------------

__global__ __launch_bounds__(256) void gat_agg_kernel(
    const float* __restrict__ xl, const float* __restrict__ xr,
    const int* __restrict__ row_start, const int* __restrict__ degv,
    const int* __restrict__ csr_src,
    const float* __restrict__ att, const float* __restrict__ bias,
    const float* __restrict__ bn_scale, const float* __restrict__ bn_shift,
    float* __restrict__ out, int n, int use_bn)
{
    int wave = (int)((blockIdx.x * 256 + threadIdx.x) >> 6);
    int lane = threadIdx.x & 63;
    if (wave >= n) return;
    int grp = lane >> 4;
    int gl  = lane & 15;
    int f   = gl * 8;

    float4 xr0 = *(const float4*)&xr[(size_t)wave * DD + f];
    float4 xr1 = *(const float4*)&xr[(size_t)wave * DD + f + 4];
    float4 at0 = *(const float4*)&att[f];
    float4 at1 = *(const float4*)&att[f + 4];

    int nstart = row_start[wave];
    int deg = degv[wave];

    float acc[8] = {0.f, 0.f, 0.f, 0.f, 0.f, 0.f, 0.f, 0.f};
    float den = 0.f;

    for (int j = grp; j < deg; j += 4) {
        int s = csr_src[nstart + j];
        const float* xp = &xl[(size_t)s * DD + f];
        float4 a0 = *(const float4*)xp;
        float4 a1 = *(const float4*)(xp + 4);
        float t, partial;
        t = a0.x + xr0.x; t = t > 0.f ? t : SLOPE * t; partial  = at0.x * t;
        t = a0.y + xr0.y; t = t > 0.f ? t : SLOPE * t; partial += at0.y * t;
        t = a0.z + xr0.z; t = t > 0.f ? t : SLOPE * t; partial += at0.z * t;
        t = a0.w + xr0.w; t = t > 0.f ? t : SLOPE * t; partial += at0.w * t;
        t = a1.x + xr1.x; t = t > 0.f ? t : SLOPE * t; partial += at1.x * t;
        t = a1.y + xr1.y; t = t > 0.f ? t : SLOPE * t; partial += at1.y * t;
        t = a1.z + xr1.z; t = t > 0.f ? t : SLOPE * t; partial += at1.z * t;
        t = a1.w + xr1.w; t = t > 0.f ? t : SLOPE * t; partial += at1.w * t;
        partial += __shfl_xor(partial, 1, 64);
        partial += __shfl_xor(partial, 2, 64);
        partial += __shfl_xor(partial, 4, 64);
        partial += __shfl_xor(partial, 8, 64);
        float p = __expf(partial);
        den += p;
        acc[0] += p * a0.x; acc[1] += p * a0.y; acc[2] += p * a0.z; acc[3] += p * a0.w;
        acc[4] += p * a1.x; acc[5] += p * a1.y; acc[6] += p * a1.z; acc[7] += p * a1.w;
    }

    #pragma unroll
    for (int k = 0; k < 8; ++k) {
        acc[k] += __shfl_xor(acc[k], 16, 64);
        acc[k] += __shfl_xor(acc[k], 32, 64);
    }
    den += __shfl_xor(den, 16, 64);
    den += __shfl_xor(den, 32, 64);

    if (grp == 0) {
        float inv = (deg > 0) ? 1.0f / den : 0.0f;
        float o[8];
        #pragma unroll
        for (int k = 0; k < 8; ++k) o[k] = acc[k] * inv + bias[f + k];
        if (use_bn) {
            #pragma unroll
            for (int k = 0; k < 8; ++k) {
                o[k] = o[k] * bn_scale[f + k] + bn_shift[f + k];
                o[k] = o[k] > 0.f ? o[k] : 0.f;
            }
        }
        *(float4*)&out[(size_t)wave * DD + f]     = make_float4(o[0], o[1], o[2], o[3]);
        *(float4*)&out[(size_t)wave * DD + f + 4] = make_float4(o[4], o[5], o[6], o[7]);
    }
}

// ---------------- global mean pool ----------------

__device__ __forceinline__ int lower_bound_dev(const int* __restrict__ arr, int n, int val) {
    int lo = 0, hi = n;
    while (lo < hi) {
        int mid = (lo + hi) >> 1;
        if (arr[mid] < val) lo = mid + 1; else hi = mid;
    }
    return lo;
}

__global__ __launch_bounds__(512) void pool_kernel(const float* __restrict__ h,
                                                   const int* __restrict__ batch,
                                                   float* __restrict__ pooled, int n) {
    __shared__ float red[4][DD];
    int g = blockIdx.x;
    int f = threadIdx.x & 127;
    int rg = threadIdx.x >> 7;     // 0..3
    int lo = lower_bound_dev(batch, n, g);
    int hi = lower_bound_dev(batch, n, g + 1);
    float s = 0.f;
    for (int i = lo + rg; i < hi; i += 4) s += h[(size_t)i * DD + f];
    red[rg][f] = s;
    __syncthreads();
    if (rg == 0) {
        float tot = red[0][f] + red[1][f] + red[2][f] + red[3][f];
        float cnt = (float)(hi - lo);
        pooled[(size_t)g * DD + f] = tot / fmaxf(cnt, 1.0f);
    }
}

// ---------------- fused head ----------------

__global__ __launch_bounds__(64) void head_kernel(
    const float* __restrict__ pooled, const float* __restrict__ fc1_w,
    const float* __restrict__ fc1_b, const float* __restrict__ fc3_w,
    const float* __restrict__ fc3_b, float* __restrict__ out)
{
    int sIdx = blockIdx.x;
    int gbase = blockIdx.y * 20;
    int j = threadIdx.x;

    float wreg[DD];
    #pragma unroll
    for (int k = 0; k < DD; ++k)
        wreg[k] = fc1_w[(size_t)k * (NSTK * 64) + sIdx * 64 + j];
    float b1 = fc1_b[sIdx * 64 + j];
    float w3 = fc3_w[j];
    float b3 = fc3_b[0];

    for (int gi = 0; gi < 20; ++gi) {
        int g = gbase + gi;
        float acc = b1;
        #pragma unroll
        for (int k4 = 0; k4 < DD / 4; ++k4) {
            float4 pv = *(const float4*)&pooled[(size_t)g * DD + k4 * 4];
            acc += pv.x * wreg[k4 * 4 + 0];
            acc += pv.y * wreg[k4 * 4 + 1];
            acc += pv.z * wreg[k4 * 4 + 2];
            acc += pv.w * wreg[k4 * 4 + 3];
        }
        float r = acc > 0.f ? acc : 0.f;
        float v = r * w3;
        #pragma unroll
        for (int off = 32; off; off >>= 1) v += __shfl_xor(v, off, 64);
        if (j == 0) out[(size_t)g * NSTK + sIdx] = 1.0f / (1.0f + __expf(-(v + b3)));
    }
}

// ---------------- launch ----------------

extern "C" void kernel_launch(void* const* d_in, const int* in_sizes, int n_in,
                              void* d_out, int out_size, void* d_ws, size_t ws_size,
                              hipStream_t stream) {
    const float* x        = (const float*)d_in[0];
    const int*   graph    = (const int*)d_in[1];
    const int*   batch    = (const int*)d_in[2];
    const float* wl0      = (const float*)d_in[3];
    const float* bl0      = (const float*)d_in[4];
    const float* wr0      = (const float*)d_in[5];
    const float* br0      = (const float*)d_in[6];
    const float* att0     = (const float*)d_in[7];
    const float* b0       = (const float*)d_in[8];
    const float* wl1      = (const float*)d_in[9];
    const float* bl1      = (const float*)d_in[10];
    const float* wr1      = (const float*)d_in[11];
    const float* br1      = (const float*)d_in[12];
    const float* att1     = (const float*)d_in[13];
    const float* b1       = (const float*)d_in[14];
    const float* bn_gamma = (const float*)d_in[15];
    const float* bn_beta  = (const float*)d_in[16];
    const float* bn_mean  = (const float*)d_in[17];
    const float* bn_var   = (const float*)d_in[18];
    const float* fc1_w    = (const float*)d_in[19];
    const float* fc1_b    = (const float*)d_in[20];
    const float* fc3_w    = (const float*)d_in[21];
    const float* fc3_b    = (const float*)d_in[22];
    float* out = (float*)d_out;

    int n       = in_sizes[0] / DD;   // 50000
    int e_count = in_sizes[1] / 2;    // 800000
    const int* srcv = graph;
    const int* dstv = graph + e_count;

    float* A        = (float*)d_ws;
    float* B        = A + (size_t)n * DD;
    float* C        = B + (size_t)n * DD;
    float* pooled   = C + (size_t)n * DD;
    float* bn_scale = pooled + (size_t)GG * DD;
    float* bn_shift = bn_scale + DD;
    int* deg     = (int*)(bn_shift + DD);
    int* total   = deg + n;
    int* start   = total + 1;
    int* cursor  = start + n;
    int* csr_src = cursor + n;
    uintptr_t wp = ((uintptr_t)(csr_src + e_count) + 15) & ~(uintptr_t)15;
    unsigned short* wt0 = (unsigned short*)wp;          // [256][128] bf16
    unsigned short* wt1 = wt0 + 256 * DD;

    hipMemsetAsync(deg, 0, (size_t)(n + 1) * sizeof(int), stream);
    hist_kernel<<<(e_count + 255) / 256, 256, 0, stream>>>(dstv, deg, e_count);
    offsets_kernel<<<(n + 255) / 256, 256, 0, stream>>>(deg, start, cursor, total, n);
    scatter_kernel<<<(e_count + 255) / 256, 256, 0, stream>>>(srcv, dstv, cursor, csr_src, e_count);
    bn_prep_kernel<<<1, DD, 0, stream>>>(bn_gamma, bn_beta, bn_mean, bn_var, bn_scale, bn_shift);
    wprep_kernel<<<dim3(256, 2), 128, 0, stream>>>(wl0, wr0, wl1, wr1, wt0, wt1);

    int mmblocks = (n + 63) / 64;
    int aggblocks = (n + 3) / 4;

    dualmm_mfma_kernel<<<dim3(mmblocks, 2), 256, 0, stream>>>(x, wt0, bl0, br0, A, B, n);
    gat_agg_kernel<<<aggblocks, 256, 0, stream>>>(A, B, start, deg, csr_src, att0, b0,
                                                  bn_scale, bn_shift, C, n, 1);
    dualmm_mfma_kernel<<<dim3(mmblocks, 2), 256, 0, stream>>>(C, wt1, bl1, br1, A, B, n);
    gat_agg_kernel<<<aggblocks, 256, 0, stream>>>(A, B, start, deg, csr_src, att1, b1,
                                                  nullptr, nullptr, C, n, 0);
    pool_kernel<<<GG, 512, 0, stream>>>(C, batch, pooled, n);
    head_kernel<<<dim3(NSTK, GG / 20), 64, 0, stream>>>(pooled, fc1_w, fc1_b, fc3_w, fc3_b, out);
}

// Round 4
// 398.252 us; speedup vs baseline: 1.6837x; 1.0890x over previous
//
#include <hip/hip_runtime.h>

#define DD 128
#define GG 500
#define NSTK 100
#define SLOPE 0.2f
#define BN_EPS 1e-5f
#define XPAD 136   // LDS row stride in bf16 elems (128 + 8 pad)

typedef __attribute__((ext_vector_type(8))) short bf16x8;
typedef __attribute__((ext_vector_type(4))) float f32x4;
typedef unsigned int uint;

static __device__ __forceinline__ unsigned short f2bf(float f) {
    union { float f; unsigned int u; } v; v.f = f;
    unsigned int r = (v.u + 0x7fff + ((v.u >> 16) & 1)) >> 16;   // RNE
    return (unsigned short)r;
}

static __device__ __forceinline__ void unpack8(uint4 u, float* o) {
    union { uint u; float f; } c;
    c.u = u.x << 16;         o[0] = c.f;
    c.u = u.x & 0xffff0000u; o[1] = c.f;
    c.u = u.y << 16;         o[2] = c.f;
    c.u = u.y & 0xffff0000u; o[3] = c.f;
    c.u = u.z << 16;         o[4] = c.f;
    c.u = u.z & 0xffff0000u; o[5] = c.f;
    c.u = u.w << 16;         o[6] = c.f;
    c.u = u.w & 0xffff0000u; o[7] = c.f;
}

// ---------------- CSR build ----------------

__global__ __launch_bounds__(256) void hist_kernel(const int* __restrict__ dst,
                                                   int* __restrict__ deg, int e_count) {
    int e = blockIdx.x * 256 + threadIdx.x;
    if (e < e_count) atomicAdd(&deg[dst[e]], 1);
}

__global__ __launch_bounds__(256) void offsets_kernel(const int* __restrict__ deg,
                                                      int* __restrict__ start,
                                                      int* __restrict__ cursor,
                                                      int* __restrict__ total, int n) {
    int i = blockIdx.x * 256 + threadIdx.x;
    int lane = threadIdx.x & 63;
    int d = (i < n) ? deg[i] : 0;
    int pre = d;
    #pragma unroll
    for (int off = 1; off < 64; off <<= 1) {
        int t = __shfl_up(pre, off, 64);
        if (lane >= off) pre += t;
    }
    int wavesum = __shfl(pre, 63, 64);
    int base = 0;
    if (lane == 0) base = atomicAdd(total, wavesum);
    base = __shfl(base, 0, 64);
    if (i < n) {
        int s0 = base + pre - d;
        start[i] = s0;
        cursor[i] = s0;
    }
}

__global__ __launch_bounds__(256) void scatter_kernel(const int* __restrict__ src,
                                                      const int* __restrict__ dst,
                                                      int* __restrict__ cursor,
                                                      int* __restrict__ csr_src, int e_count) {
    int e = blockIdx.x * 256 + threadIdx.x;
    if (e < e_count) {
        int d = dst[e];
        int p = atomicAdd(&cursor[d], 1);
        csr_src[p] = src[e];
    }
}

__global__ void bn_prep_kernel(const float* __restrict__ g, const float* __restrict__ b,
                               const float* __restrict__ m, const float* __restrict__ v,
                               float* __restrict__ scale, float* __restrict__ shift) {
    int i = threadIdx.x;
    float s = g[i] * rsqrtf(v[i] + BN_EPS);
    scale[i] = s;
    shift[i] = b[i] - m[i] * s;
}

// ---------------- weight prep: WT[c][k] bf16, c in [0,256): [wl | wr] transposed ----------------

__global__ __launch_bounds__(128) void wprep_kernel(
    const float* __restrict__ wl0, const float* __restrict__ wr0,
    const float* __restrict__ wl1, const float* __restrict__ wr1,
    unsigned short* __restrict__ wt0, unsigned short* __restrict__ wt1)
{
    int c = blockIdx.x;
    int layer = blockIdx.y;
    int k = threadIdx.x;
    const float* wl = layer ? wl1 : wl0;
    const float* wr = layer ? wr1 : wr0;
    float v = (c < 128) ? wl[k * DD + c] : wr[k * DD + (c - 128)];
    unsigned short* wt = layer ? wt1 : wt0;
    wt[c * DD + k] = f2bf(v);
}

// ---------------- dual matmul via MFMA: outA = x@wl + bl (bf16), outB = x@wr + br (bf16) ----------
// 64 rows/block, x staged ONCE; wsh restaged per col-half inside the block.
// input: xf (f32, layer 0) or xbf (bf16, layer 1) -- exactly one non-null.

__global__ __launch_bounds__(256) void dualmm_mfma_kernel(
    const float* __restrict__ xf, const unsigned short* __restrict__ xbf,
    const unsigned short* __restrict__ wt,
    const float* __restrict__ bA, const float* __restrict__ bB,
    unsigned short* __restrict__ outA, unsigned short* __restrict__ outB, int n)
{
    __shared__ unsigned short xs[64 * XPAD];    // 17408 B
    __shared__ unsigned short wsh[128 * XPAD];  // 34816 B
    int t = threadIdx.x;
    int row0 = blockIdx.x * 64;

    if (xbf) {
        #pragma unroll
        for (int i = 0; i < 4; ++i) {
            int idx = i * 256 + t;             // 0..1023 chunks of 8 bf16
            int r = idx >> 4;
            int c = (idx & 15) * 8;
            uint4 v = make_uint4(0, 0, 0, 0);
            if (row0 + r < n) v = *(const uint4*)&xbf[(size_t)(row0 + r) * DD + c];
            *(uint4*)&xs[r * XPAD + c] = v;
        }
    } else {
        #pragma unroll
        for (int i = 0; i < 4; ++i) {
            int idx8 = i * 256 + t;
            int r = idx8 >> 4;
            int c = (idx8 & 15) * 8;
            float4 v0 = make_float4(0.f, 0.f, 0.f, 0.f), v1 = v0;
            if (row0 + r < n) {
                v0 = *(const float4*)&xf[(size_t)(row0 + r) * DD + c];
                v1 = *(const float4*)&xf[(size_t)(row0 + r) * DD + c + 4];
            }
            union { bf16x8 v; unsigned short u[8]; } pk;
            pk.u[0] = f2bf(v0.x); pk.u[1] = f2bf(v0.y); pk.u[2] = f2bf(v0.z); pk.u[3] = f2bf(v0.w);
            pk.u[4] = f2bf(v1.x); pk.u[5] = f2bf(v1.y); pk.u[6] = f2bf(v1.z); pk.u[7] = f2bf(v1.w);
            *(bf16x8*)&xs[r * XPAD + c] = pk.v;
        }
    }

    int wave = t >> 6, lane = t & 63;
    int m16 = lane & 15;
    int kg = lane >> 4;

    for (int half = 0; half < 2; ++half) {
        __syncthreads();   // x-stage done (half 0) / previous half's LDS reads done (half 1)
        #pragma unroll
        for (int i = 0; i < 8; ++i) {
            int idx = i * 256 + t;             // 0..2047 chunks of 8 bf16
            int r = idx >> 4;
            int ck = (idx & 15) * 8;
            uint4 v = *(const uint4*)&wt[(size_t)(half * 128 + r) * DD + ck];
            *(uint4*)&wsh[r * XPAD + ck] = v;
        }
        __syncthreads();

        f32x4 acc[4][2];
        #pragma unroll
        for (int rt = 0; rt < 4; ++rt)
            #pragma unroll
            for (int ct = 0; ct < 2; ++ct)
                acc[rt][ct] = (f32x4){0.f, 0.f, 0.f, 0.f};

        #pragma unroll
        for (int ks = 0; ks < 4; ++ks) {
            int koff = ks * 32 + kg * 8;
            bf16x8 a[4], b[2];
            #pragma unroll
            for (int rt = 0; rt < 4; ++rt)
                a[rt] = *(bf16x8*)&xs[(rt * 16 + m16) * XPAD + koff];
            #pragma unroll
            for (int ct = 0; ct < 2; ++ct)
                b[ct] = *(bf16x8*)&wsh[(wave * 32 + ct * 16 + m16) * XPAD + koff];
            #pragma unroll
            for (int rt = 0; rt < 4; ++rt)
                #pragma unroll
                for (int ct = 0; ct < 2; ++ct)
                    acc[rt][ct] = __builtin_amdgcn_mfma_f32_16x16x32_bf16(a[rt], b[ct], acc[rt][ct], 0, 0, 0);
        }

        const float* bias = half ? bB : bA;
        unsigned short* outp = half ? outB : outA;
        #pragma unroll
        for (int rt = 0; rt < 4; ++rt) {
            int r = row0 + rt * 16 + kg * 4;
            #pragma unroll
            for (int ct = 0; ct < 2; ++ct) {
                int c = wave * 32 + ct * 16 + m16;
                float bb = bias[c];
                #pragma unroll
                for (int i = 0; i < 4; ++i) {
                    if (r + i < n)
                        outp[(size_t)(r + i) * DD + c] = f2bf(acc[rt][ct][i] + bb);
                }
            }
        }
    }
}

// ---------------- fused GATv2 edge phase (bf16 activations) ----------------
// one wave per dst node; 4 groups of 16 lanes = 4 gather chains; lane covers 8 dims (16 B).

__global__ __launch_bounds__(256) void gat_agg_kernel(
    const unsigned short* __restrict__ xl, const unsigned short* __restrict__ xr,
    const int* __restrict__ row_start, const int* __restrict__ degv,
    const int* __restrict__ csr_src,
    const float* __restrict__ att, const float* __restrict__ bias,
    const float* __restrict__ bn_scale, const float* __restrict__ bn_shift,
    unsigned short* __restrict__ out_bf, float* __restrict__ out_f32,
    int n, int use_bn)
{
    int wave = (int)((blockIdx.x * 256 + threadIdx.x) >> 6);
    int lane = threadIdx.x & 63;
    if (wave >= n) return;
    int grp = lane >> 4;
    int gl  = lane & 15;
    int f   = gl * 8;

    float xrv[8];
    unpack8(*(const uint4*)&xr[(size_t)wave * DD + f], xrv);
    float atv[8];
    *(float4*)&atv[0] = *(const float4*)&att[f];
    *(float4*)&atv[4] = *(const float4*)&att[f + 4];

    int nstart = row_start[wave];
    int deg = degv[wave];

    float acc[8] = {0.f, 0.f, 0.f, 0.f, 0.f, 0.f, 0.f, 0.f};
    float den = 0.f;

    for (int j = grp; j < deg; j += 4) {
        int s = csr_src[nstart + j];
        uint4 au = *(const uint4*)&xl[(size_t)s * DD + f];
        float a[8];
        unpack8(au, a);
        float partial = 0.f;
        #pragma unroll
        for (int k = 0; k < 8; ++k) {
            float t = a[k] + xrv[k];
            t = t > 0.f ? t : SLOPE * t;
            partial += atv[k] * t;
        }
        partial += __shfl_xor(partial, 1, 64);
        partial += __shfl_xor(partial, 2, 64);
        partial += __shfl_xor(partial, 4, 64);
        partial += __shfl_xor(partial, 8, 64);
        float p = __expf(partial);
        den += p;
        #pragma unroll
        for (int k = 0; k < 8; ++k) acc[k] += p * a[k];
    }

    #pragma unroll
    for (int k = 0; k < 8; ++k) {
        acc[k] += __shfl_xor(acc[k], 16, 64);
        acc[k] += __shfl_xor(acc[k], 32, 64);
    }
    den += __shfl_xor(den, 16, 64);
    den += __shfl_xor(den, 32, 64);

    if (grp == 0) {
        float inv = (deg > 0) ? 1.0f / den : 0.0f;
        float o[8];
        #pragma unroll
        for (int k = 0; k < 8; ++k) o[k] = acc[k] * inv + bias[f + k];
        if (use_bn) {
            #pragma unroll
            for (int k = 0; k < 8; ++k) {
                o[k] = o[k] * bn_scale[f + k] + bn_shift[f + k];
                o[k] = o[k] > 0.f ? o[k] : 0.f;
            }
        }
        if (out_bf) {
            uint4 pk;
            pk.x = ((uint)f2bf(o[1]) << 16) | f2bf(o[0]);
            pk.y = ((uint)f2bf(o[3]) << 16) | f2bf(o[2]);
            pk.z = ((uint)f2bf(o[5]) << 16) | f2bf(o[4]);
            pk.w = ((uint)f2bf(o[7]) << 16) | f2bf(o[6]);
            *(uint4*)&out_bf[(size_t)wave * DD + f] = pk;
        } else {
            *(float4*)&out_f32[(size_t)wave * DD + f]     = make_float4(o[0], o[1], o[2], o[3]);
            *(float4*)&out_f32[(size_t)wave * DD + f + 4] = make_float4(o[4], o[5], o[6], o[7]);
        }
    }
}

// ---------------- global mean pool ----------------

__device__ __forceinline__ int lower_bound_dev(const int* __restrict__ arr, int n, int val) {
    int lo = 0, hi = n;
    while (lo < hi) {
        int mid = (lo + hi) >> 1;
        if (arr[mid] < val) lo = mid + 1; else hi = mid;
    }
    return lo;
}

__global__ __launch_bounds__(512) void pool_kernel(const float* __restrict__ h,
                                                   const int* __restrict__ batch,
                                                   float* __restrict__ pooled, int n) {
    __shared__ float red[4][DD];
    int g = blockIdx.x;
    int f = threadIdx.x & 127;
    int rg = threadIdx.x >> 7;
    int lo = lower_bound_dev(batch, n, g);
    int hi = lower_bound_dev(batch, n, g + 1);
    float s = 0.f;
    for (int i = lo + rg; i < hi; i += 4) s += h[(size_t)i * DD + f];
    red[rg][f] = s;
    __syncthreads();
    if (rg == 0) {
        float tot = red[0][f] + red[1][f] + red[2][f] + red[3][f];
        float cnt = (float)(hi - lo);
        pooled[(size_t)g * DD + f] = tot / fmaxf(cnt, 1.0f);
    }
}

// ---------------- fused head ----------------

__global__ __launch_bounds__(64) void head_kernel(
    const float* __restrict__ pooled, const float* __restrict__ fc1_w,
    const float* __restrict__ fc1_b, const float* __restrict__ fc3_w,
    const float* __restrict__ fc3_b, float* __restrict__ out)
{
    int sIdx = blockIdx.x;
    int gbase = blockIdx.y * 20;
    int j = threadIdx.x;

    float wreg[DD];
    #pragma unroll
    for (int k = 0; k < DD; ++k)
        wreg[k] = fc1_w[(size_t)k * (NSTK * 64) + sIdx * 64 + j];
    float b1 = fc1_b[sIdx * 64 + j];
    float w3 = fc3_w[j];
    float b3 = fc3_b[0];

    for (int gi = 0; gi < 20; ++gi) {
        int g = gbase + gi;
        float acc = b1;
        #pragma unroll
        for (int k4 = 0; k4 < DD / 4; ++k4) {
            float4 pv = *(const float4*)&pooled[(size_t)g * DD + k4 * 4];
            acc += pv.x * wreg[k4 * 4 + 0];
            acc += pv.y * wreg[k4 * 4 + 1];
            acc += pv.z * wreg[k4 * 4 + 2];
            acc += pv.w * wreg[k4 * 4 + 3];
        }
        float r = acc > 0.f ? acc : 0.f;
        float v = r * w3;
        #pragma unroll
        for (int off = 32; off; off >>= 1) v += __shfl_xor(v, off, 64);
        if (j == 0) out[(size_t)g * NSTK + sIdx] = 1.0f / (1.0f + __expf(-(v + b3)));
    }
}

// ---------------- launch ----------------

extern "C" void kernel_launch(void* const* d_in, const int* in_sizes, int n_in,
                              void* d_out, int out_size, void* d_ws, size_t ws_size,
                              hipStream_t stream) {
    const float* x        = (const float*)d_in[0];
    const int*   graph    = (const int*)d_in[1];
    const int*   batch    = (const int*)d_in[2];
    const float* wl0      = (const float*)d_in[3];
    const float* bl0      = (const float*)d_in[4];
    const float* wr0      = (const float*)d_in[5];
    const float* br0      = (const float*)d_in[6];
    const float* att0     = (const float*)d_in[7];
    const float* b0       = (const float*)d_in[8];
    const float* wl1      = (const float*)d_in[9];
    const float* bl1      = (const float*)d_in[10];
    const float* wr1      = (const float*)d_in[11];
    const float* br1      = (const float*)d_in[12];
    const float* att1     = (const float*)d_in[13];
    const float* b1       = (const float*)d_in[14];
    const float* bn_gamma = (const float*)d_in[15];
    const float* bn_beta  = (const float*)d_in[16];
    const float* bn_mean  = (const float*)d_in[17];
    const float* bn_var   = (const float*)d_in[18];
    const float* fc1_w    = (const float*)d_in[19];
    const float* fc1_b    = (const float*)d_in[20];
    const float* fc3_w    = (const float*)d_in[21];
    const float* fc3_b    = (const float*)d_in[22];
    float* out = (float*)d_out;

    int n       = in_sizes[0] / DD;   // 50000
    int e_count = in_sizes[1] / 2;    // 800000
    const int* srcv = graph;
    const int* dstv = graph + e_count;

    // workspace layout
    unsigned short* A  = (unsigned short*)d_ws;        // xl bf16 [n*DD]
    unsigned short* B  = A + (size_t)n * DD;           // xr bf16 [n*DD]
    unsigned short* Cb = B + (size_t)n * DD;           // h  bf16 [n*DD]
    float* Cf        = (float*)(Cb + (size_t)n * DD);  // layer1 out f32 [n*DD]
    float* pooled    = Cf + (size_t)n * DD;            // [GG*DD]
    float* bn_scale  = pooled + (size_t)GG * DD;       // [DD]
    float* bn_shift  = bn_scale + DD;                  // [DD]
    int* deg     = (int*)(bn_shift + DD);              // [n]
    int* total   = deg + n;                            // [1]
    int* start   = total + 1;                          // [n]
    int* cursor  = start + n;                          // [n]
    int* csr_src = cursor + n;                         // [e_count]
    uintptr_t wp = ((uintptr_t)(csr_src + e_count) + 15) & ~(uintptr_t)15;
    unsigned short* wt0 = (unsigned short*)wp;         // [256][128] bf16
    unsigned short* wt1 = wt0 + 256 * DD;

    hipMemsetAsync(deg, 0, (size_t)(n + 1) * sizeof(int), stream);
    hist_kernel<<<(e_count + 255) / 256, 256, 0, stream>>>(dstv, deg, e_count);
    offsets_kernel<<<(n + 255) / 256, 256, 0, stream>>>(deg, start, cursor, total, n);
    scatter_kernel<<<(e_count + 255) / 256, 256, 0, stream>>>(srcv, dstv, cursor, csr_src, e_count);
    bn_prep_kernel<<<1, DD, 0, stream>>>(bn_gamma, bn_beta, bn_mean, bn_var, bn_scale, bn_shift);
    wprep_kernel<<<dim3(256, 2), 128, 0, stream>>>(wl0, wr0, wl1, wr1, wt0, wt1);

    int mmblocks = (n + 63) / 64;
    int aggblocks = (n + 3) / 4;

    dualmm_mfma_kernel<<<mmblocks, 256, 0, stream>>>(x, nullptr, wt0, bl0, br0, A, B, n);
    gat_agg_kernel<<<aggblocks, 256, 0, stream>>>(A, B, start, deg, csr_src, att0, b0,
                                                  bn_scale, bn_shift, Cb, nullptr, n, 1);
    dualmm_mfma_kernel<<<mmblocks, 256, 0, stream>>>(nullptr, Cb, wt1, bl1, br1, A, B, n);
    gat_agg_kernel<<<aggblocks, 256, 0, stream>>>(A, B, start, deg, csr_src, att1, b1,
                                                  nullptr, nullptr, nullptr, Cf, n, 0);
    pool_kernel<<<GG, 512, 0, stream>>>(Cf, batch, pooled, n);
    head_kernel<<<dim3(NSTK, GG / 20), 64, 0, stream>>>(pooled, fc1_w, fc1_b, fc3_w, fc3_b, out);
}

// Round 5
// 394.270 us; speedup vs baseline: 1.7007x; 1.0101x over previous
//
#include <hip/hip_runtime.h>

#define DD 128
#define GG 500
#define NSTK 100
#define SLOPE 0.2f
#define BN_EPS 1e-5f
#define XPAD 136   // LDS row stride in bf16 elems (128 + 8 pad)

typedef __attribute__((ext_vector_type(8))) short bf16x8;
typedef __attribute__((ext_vector_type(4))) float f32x4;
typedef __attribute__((ext_vector_type(2))) float f32x2;
typedef unsigned int uint;

static __device__ __forceinline__ unsigned short f2bf(float f) {
    union { float f; unsigned int u; } v; v.f = f;
    unsigned int r = (v.u + 0x7fff + ((v.u >> 16) & 1)) >> 16;   // RNE
    return (unsigned short)r;
}

// two packed bf16 -> f32x2 (low elem -> .x, high elem -> .y)
static __device__ __forceinline__ f32x2 bfpair(uint u) {
    union { uint2 u2; f32x2 f; } c;
    c.u2.x = u << 16;
    c.u2.y = u & 0xffff0000u;
    return c.f;
}

// ---------------- CSR build ----------------

__global__ __launch_bounds__(256) void hist_kernel(const int* __restrict__ dst,
                                                   int* __restrict__ deg, int e_count) {
    int e = blockIdx.x * 256 + threadIdx.x;
    if (e < e_count) atomicAdd(&deg[dst[e]], 1);
}

__global__ __launch_bounds__(256) void offsets_kernel(const int* __restrict__ deg,
                                                      int* __restrict__ start,
                                                      int* __restrict__ cursor,
                                                      int* __restrict__ total, int n) {
    int i = blockIdx.x * 256 + threadIdx.x;
    int lane = threadIdx.x & 63;
    int d = (i < n) ? deg[i] : 0;
    int pre = d;
    #pragma unroll
    for (int off = 1; off < 64; off <<= 1) {
        int t = __shfl_up(pre, off, 64);
        if (lane >= off) pre += t;
    }
    int wavesum = __shfl(pre, 63, 64);
    int base = 0;
    if (lane == 0) base = atomicAdd(total, wavesum);
    base = __shfl(base, 0, 64);
    if (i < n) {
        int s0 = base + pre - d;
        start[i] = s0;
        cursor[i] = s0;
    }
}

__global__ __launch_bounds__(256) void scatter_kernel(const int* __restrict__ src,
                                                      const int* __restrict__ dst,
                                                      int* __restrict__ cursor,
                                                      int* __restrict__ csr_src, int e_count) {
    int e = blockIdx.x * 256 + threadIdx.x;
    if (e < e_count) {
        int d = dst[e];
        int p = atomicAdd(&cursor[d], 1);
        csr_src[p] = src[e];
    }
}

// ---------------- weight prep (bn folded into block (0,0)) ----------------

__global__ __launch_bounds__(128) void wprep_kernel(
    const float* __restrict__ wl0, const float* __restrict__ wr0,
    const float* __restrict__ wl1, const float* __restrict__ wr1,
    unsigned short* __restrict__ wt0, unsigned short* __restrict__ wt1,
    const float* __restrict__ bn_g, const float* __restrict__ bn_b,
    const float* __restrict__ bn_m, const float* __restrict__ bn_v,
    float* __restrict__ bn_scale, float* __restrict__ bn_shift)
{
    int c = blockIdx.x;
    int layer = blockIdx.y;
    int k = threadIdx.x;
    const float* wl = layer ? wl1 : wl0;
    const float* wr = layer ? wr1 : wr0;
    float v = (c < 128) ? wl[k * DD + c] : wr[k * DD + (c - 128)];
    unsigned short* wt = layer ? wt1 : wt0;
    wt[c * DD + k] = f2bf(v);
    if (c == 0 && layer == 0) {
        float s = bn_g[k] * rsqrtf(bn_v[k] + BN_EPS);
        bn_scale[k] = s;
        bn_shift[k] = bn_b[k] - bn_m[k] * s;
    }
}

// ---------------- dual matmul via MFMA ----------------

__global__ __launch_bounds__(256) void dualmm_mfma_kernel(
    const float* __restrict__ xf, const unsigned short* __restrict__ xbf,
    const unsigned short* __restrict__ wt,
    const float* __restrict__ bA, const float* __restrict__ bB,
    unsigned short* __restrict__ outA, unsigned short* __restrict__ outB, int n)
{
    __shared__ unsigned short xs[64 * XPAD];
    __shared__ unsigned short wsh[128 * XPAD];
    int t = threadIdx.x;
    int row0 = blockIdx.x * 64;

    if (xbf) {
        #pragma unroll
        for (int i = 0; i < 4; ++i) {
            int idx = i * 256 + t;
            int r = idx >> 4;
            int c = (idx & 15) * 8;
            uint4 v = make_uint4(0, 0, 0, 0);
            if (row0 + r < n) v = *(const uint4*)&xbf[(size_t)(row0 + r) * DD + c];
            *(uint4*)&xs[r * XPAD + c] = v;
        }
    } else {
        #pragma unroll
        for (int i = 0; i < 4; ++i) {
            int idx8 = i * 256 + t;
            int r = idx8 >> 4;
            int c = (idx8 & 15) * 8;
            float4 v0 = make_float4(0.f, 0.f, 0.f, 0.f), v1 = v0;
            if (row0 + r < n) {
                v0 = *(const float4*)&xf[(size_t)(row0 + r) * DD + c];
                v1 = *(const float4*)&xf[(size_t)(row0 + r) * DD + c + 4];
            }
            union { bf16x8 v; unsigned short u[8]; } pk;
            pk.u[0] = f2bf(v0.x); pk.u[1] = f2bf(v0.y); pk.u[2] = f2bf(v0.z); pk.u[3] = f2bf(v0.w);
            pk.u[4] = f2bf(v1.x); pk.u[5] = f2bf(v1.y); pk.u[6] = f2bf(v1.z); pk.u[7] = f2bf(v1.w);
            *(bf16x8*)&xs[r * XPAD + c] = pk.v;
        }
    }

    int wave = t >> 6, lane = t & 63;
    int m16 = lane & 15;
    int kg = lane >> 4;

    for (int half = 0; half < 2; ++half) {
        __syncthreads();
        #pragma unroll
        for (int i = 0; i < 8; ++i) {
            int idx = i * 256 + t;
            int r = idx >> 4;
            int ck = (idx & 15) * 8;
            uint4 v = *(const uint4*)&wt[(size_t)(half * 128 + r) * DD + ck];
            *(uint4*)&wsh[r * XPAD + ck] = v;
        }
        __syncthreads();

        f32x4 acc[4][2];
        #pragma unroll
        for (int rt = 0; rt < 4; ++rt)
            #pragma unroll
            for (int ct = 0; ct < 2; ++ct)
                acc[rt][ct] = (f32x4){0.f, 0.f, 0.f, 0.f};

        #pragma unroll
        for (int ks = 0; ks < 4; ++ks) {
            int koff = ks * 32 + kg * 8;
            bf16x8 a[4], b[2];
            #pragma unroll
            for (int rt = 0; rt < 4; ++rt)
                a[rt] = *(bf16x8*)&xs[(rt * 16 + m16) * XPAD + koff];
            #pragma unroll
            for (int ct = 0; ct < 2; ++ct)
                b[ct] = *(bf16x8*)&wsh[(wave * 32 + ct * 16 + m16) * XPAD + koff];
            #pragma unroll
            for (int rt = 0; rt < 4; ++rt)
                #pragma unroll
                for (int ct = 0; ct < 2; ++ct)
                    acc[rt][ct] = __builtin_amdgcn_mfma_f32_16x16x32_bf16(a[rt], b[ct], acc[rt][ct], 0, 0, 0);
        }

        const float* bias = half ? bB : bA;
        unsigned short* outp = half ? outB : outA;
        #pragma unroll
        for (int rt = 0; rt < 4; ++rt) {
            int r = row0 + rt * 16 + kg * 4;
            #pragma unroll
            for (int ct = 0; ct < 2; ++ct) {
                int c = wave * 32 + ct * 16 + m16;
                float bb = bias[c];
                #pragma unroll
                for (int i = 0; i < 4; ++i) {
                    if (r + i < n)
                        outp[(size_t)(r + i) * DD + c] = f2bf(acc[rt][ct][i] + bb);
                }
            }
        }
    }
}

// ---------------- fused GATv2 edge phase (bf16, packed-f32 math, prefetch pipeline) ----------
// one wave per dst node; 4 groups of 16 lanes = 4 gather chains; lane covers 8 dims (16 B).

__global__ __launch_bounds__(256) void gat_agg_kernel(
    const unsigned short* __restrict__ xl, const unsigned short* __restrict__ xr,
    const int* __restrict__ row_start, const int* __restrict__ degv,
    const int* __restrict__ csr_src,
    const float* __restrict__ att, const float* __restrict__ bias,
    const float* __restrict__ bn_scale, const float* __restrict__ bn_shift,
    unsigned short* __restrict__ out_bf, float* __restrict__ out_f32,
    int n, int use_bn)
{
    int wave = (int)((blockIdx.x * 256 + threadIdx.x) >> 6);
    int lane = threadIdx.x & 63;
    if (wave >= n) return;
    int grp = lane >> 4;
    int gl  = lane & 15;
    int f   = gl * 8;

    uint4 xru = *(const uint4*)&xr[(size_t)wave * DD + f];
    f32x2 xrp[4] = {bfpair(xru.x), bfpair(xru.y), bfpair(xru.z), bfpair(xru.w)};
    const f32x2* attp = (const f32x2*)&att[f];
    f32x2 atp[4] = {attp[0], attp[1], attp[2], attp[3]};

    int nstart = row_start[wave];
    int deg = degv[wave];

    f32x2 accp[4] = {{0.f,0.f},{0.f,0.f},{0.f,0.f},{0.f,0.f}};
    float den = 0.f;

    // software pipeline: prefetch next edge's src row while processing current
    int j = grp;
    int s = (j < deg) ? csr_src[nstart + j] : 0;
    uint4 au = (j < deg) ? *(const uint4*)&xl[(size_t)s * DD + f] : make_uint4(0,0,0,0);

    while (j < deg) {
        int jn = j + 4;
        int sn = (jn < deg) ? csr_src[nstart + jn] : 0;
        uint4 aun = (jn < deg) ? *(const uint4*)&xl[(size_t)sn * DD + f] : make_uint4(0,0,0,0);

        f32x2 ap[4] = {bfpair(au.x), bfpair(au.y), bfpair(au.z), bfpair(au.w)};
        f32x2 ld = {0.f, 0.f};
        #pragma unroll
        for (int k = 0; k < 4; ++k) {
            f32x2 tv = ap[k] + xrp[k];
            f32x2 lr = __builtin_elementwise_max(tv, SLOPE * tv);   // leaky-relu, packed
            ld += atp[k] * lr;
        }
        float partial = ld.x + ld.y;
        partial += __shfl_xor(partial, 1, 64);
        partial += __shfl_xor(partial, 2, 64);
        partial += __shfl_xor(partial, 4, 64);
        partial += __shfl_xor(partial, 8, 64);
        float p = __expf(partial);
        den += p;
        #pragma unroll
        for (int k = 0; k < 4; ++k) accp[k] += p * ap[k];

        au = aun;
        j = jn;
    }

    // combine the 4 groups
    float* accf = (float*)accp;
    #pragma unroll
    for (int k = 0; k < 8; ++k) {
        accf[k] += __shfl_xor(accf[k], 16, 64);
        accf[k] += __shfl_xor(accf[k], 32, 64);
    }
    den += __shfl_xor(den, 16, 64);
    den += __shfl_xor(den, 32, 64);

    if (grp == 0) {
        float inv = (deg > 0) ? 1.0f / den : 0.0f;
        float o[8];
        #pragma unroll
        for (int k = 0; k < 8; ++k) o[k] = accf[k] * inv + bias[f + k];
        if (use_bn) {
            #pragma unroll
            for (int k = 0; k < 8; ++k) {
                o[k] = o[k] * bn_scale[f + k] + bn_shift[f + k];
                o[k] = o[k] > 0.f ? o[k] : 0.f;
            }
        }
        if (out_bf) {
            uint4 pk;
            pk.x = ((uint)f2bf(o[1]) << 16) | f2bf(o[0]);
            pk.y = ((uint)f2bf(o[3]) << 16) | f2bf(o[2]);
            pk.z = ((uint)f2bf(o[5]) << 16) | f2bf(o[4]);
            pk.w = ((uint)f2bf(o[7]) << 16) | f2bf(o[6]);
            *(uint4*)&out_bf[(size_t)wave * DD + f] = pk;
        } else {
            *(float4*)&out_f32[(size_t)wave * DD + f]     = make_float4(o[0], o[1], o[2], o[3]);
            *(float4*)&out_f32[(size_t)wave * DD + f + 4] = make_float4(o[4], o[5], o[6], o[7]);
        }
    }
}

// ---------------- global mean pool ----------------

__device__ __forceinline__ int lower_bound_dev(const int* __restrict__ arr, int n, int val) {
    int lo = 0, hi = n;
    while (lo < hi) {
        int mid = (lo + hi) >> 1;
        if (arr[mid] < val) lo = mid + 1; else hi = mid;
    }
    return lo;
}

__global__ __launch_bounds__(512) void pool_kernel(const float* __restrict__ h,
                                                   const int* __restrict__ batch,
                                                   float* __restrict__ pooled, int n) {
    __shared__ float red[4][DD];
    int g = blockIdx.x;
    int f = threadIdx.x & 127;
    int rg = threadIdx.x >> 7;
    int lo = lower_bound_dev(batch, n, g);
    int hi = lower_bound_dev(batch, n, g + 1);
    float s = 0.f;
    for (int i = lo + rg; i < hi; i += 4) s += h[(size_t)i * DD + f];
    red[rg][f] = s;
    __syncthreads();
    if (rg == 0) {
        float tot = red[0][f] + red[1][f] + red[2][f] + red[3][f];
        float cnt = (float)(hi - lo);
        pooled[(size_t)g * DD + f] = tot / fmaxf(cnt, 1.0f);
    }
}

// ---------------- fused head ----------------

__global__ __launch_bounds__(64) void head_kernel(
    const float* __restrict__ pooled, const float* __restrict__ fc1_w,
    const float* __restrict__ fc1_b, const float* __restrict__ fc3_w,
    const float* __restrict__ fc3_b, float* __restrict__ out)
{
    int sIdx = blockIdx.x;
    int gbase = blockIdx.y * 20;
    int j = threadIdx.x;

    float wreg[DD];
    #pragma unroll
    for (int k = 0; k < DD; ++k)
        wreg[k] = fc1_w[(size_t)k * (NSTK * 64) + sIdx * 64 + j];
    float b1 = fc1_b[sIdx * 64 + j];
    float w3 = fc3_w[j];
    float b3 = fc3_b[0];

    for (int gi = 0; gi < 20; ++gi) {
        int g = gbase + gi;
        float acc = b1;
        #pragma unroll
        for (int k4 = 0; k4 < DD / 4; ++k4) {
            float4 pv = *(const float4*)&pooled[(size_t)g * DD + k4 * 4];
            acc += pv.x * wreg[k4 * 4 + 0];
            acc += pv.y * wreg[k4 * 4 + 1];
            acc += pv.z * wreg[k4 * 4 + 2];
            acc += pv.w * wreg[k4 * 4 + 3];
        }
        float r = acc > 0.f ? acc : 0.f;
        float v = r * w3;
        #pragma unroll
        for (int off = 32; off; off >>= 1) v += __shfl_xor(v, off, 64);
        if (j == 0) out[(size_t)g * NSTK + sIdx] = 1.0f / (1.0f + __expf(-(v + b3)));
    }
}

// ---------------- launch ----------------

extern "C" void kernel_launch(void* const* d_in, const int* in_sizes, int n_in,
                              void* d_out, int out_size, void* d_ws, size_t ws_size,
                              hipStream_t stream) {
    const float* x        = (const float*)d_in[0];
    const int*   graph    = (const int*)d_in[1];
    const int*   batch    = (const int*)d_in[2];
    const float* wl0      = (const float*)d_in[3];
    const float* bl0      = (const float*)d_in[4];
    const float* wr0      = (const float*)d_in[5];
    const float* br0      = (const float*)d_in[6];
    const float* att0     = (const float*)d_in[7];
    const float* b0       = (const float*)d_in[8];
    const float* wl1      = (const float*)d_in[9];
    const float* bl1      = (const float*)d_in[10];
    const float* wr1      = (const float*)d_in[11];
    const float* br1      = (const float*)d_in[12];
    const float* att1     = (const float*)d_in[13];
    const float* b1       = (const float*)d_in[14];
    const float* bn_gamma = (const float*)d_in[15];
    const float* bn_beta  = (const float*)d_in[16];
    const float* bn_mean  = (const float*)d_in[17];
    const float* bn_var   = (const float*)d_in[18];
    const float* fc1_w    = (const float*)d_in[19];
    const float* fc1_b    = (const float*)d_in[20];
    const float* fc3_w    = (const float*)d_in[21];
    const float* fc3_b    = (const float*)d_in[22];
    float* out = (float*)d_out;

    int n       = in_sizes[0] / DD;   // 50000
    int e_count = in_sizes[1] / 2;    // 800000
    const int* srcv = graph;
    const int* dstv = graph + e_count;

    unsigned short* A  = (unsigned short*)d_ws;
    unsigned short* B  = A + (size_t)n * DD;
    unsigned short* Cb = B + (size_t)n * DD;
    float* Cf        = (float*)(Cb + (size_t)n * DD);
    float* pooled    = Cf + (size_t)n * DD;
    float* bn_scale  = pooled + (size_t)GG * DD;
    float* bn_shift  = bn_scale + DD;
    int* deg     = (int*)(bn_shift + DD);
    int* total   = deg + n;
    int* start   = total + 1;
    int* cursor  = start + n;
    int* csr_src = cursor + n;
    uintptr_t wp = ((uintptr_t)(csr_src + e_count) + 15) & ~(uintptr_t)15;
    unsigned short* wt0 = (unsigned short*)wp;
    unsigned short* wt1 = wt0 + 256 * DD;

    hipMemsetAsync(deg, 0, (size_t)(n + 1) * sizeof(int), stream);
    hist_kernel<<<(e_count + 255) / 256, 256, 0, stream>>>(dstv, deg, e_count);
    offsets_kernel<<<(n + 255) / 256, 256, 0, stream>>>(deg, start, cursor, total, n);
    scatter_kernel<<<(e_count + 255) / 256, 256, 0, stream>>>(srcv, dstv, cursor, csr_src, e_count);
    wprep_kernel<<<dim3(256, 2), 128, 0, stream>>>(wl0, wr0, wl1, wr1, wt0, wt1,
                                                   bn_gamma, bn_beta, bn_mean, bn_var,
                                                   bn_scale, bn_shift);

    int mmblocks = (n + 63) / 64;
    int aggblocks = (n + 3) / 4;

    dualmm_mfma_kernel<<<mmblocks, 256, 0, stream>>>(x, nullptr, wt0, bl0, br0, A, B, n);
    gat_agg_kernel<<<aggblocks, 256, 0, stream>>>(A, B, start, deg, csr_src, att0, b0,
                                                  bn_scale, bn_shift, Cb, nullptr, n, 1);
    dualmm_mfma_kernel<<<mmblocks, 256, 0, stream>>>(nullptr, Cb, wt1, bl1, br1, A, B, n);
    gat_agg_kernel<<<aggblocks, 256, 0, stream>>>(A, B, start, deg, csr_src, att1, b1,
                                                  nullptr, nullptr, nullptr, Cf, n, 0);
    pool_kernel<<<GG, 512, 0, stream>>>(Cf, batch, pooled, n);
    head_kernel<<<dim3(NSTK, GG / 20), 64, 0, stream>>>(pooled, fc1_w, fc1_b, fc3_w, fc3_b, out);
}